// Round 1
// baseline (623.452 us; speedup 1.0000x reference)
//
#include <hip/hip_runtime.h>
#include <hip/hip_bf16.h>

#define B_TOK 2048
#define DDIM 1024
#define NEXP 32
#define HDIM 1024
#define TOPK 8

typedef __bf16 bf16_t;
typedef __bf16 bf16x8 __attribute__((ext_vector_type(8)));
typedef float f32x4 __attribute__((ext_vector_type(4)));

// ---------------- x -> bf16 ----------------
__global__ __launch_bounds__(256) void k_convert_x(const float* __restrict__ x,
                                                   bf16_t* __restrict__ xb) {
  int i = (blockIdx.x * 256 + threadIdx.x) * 8;
  bf16x8 v;
#pragma unroll
  for (int j = 0; j < 8; ++j) v[j] = (bf16_t)x[i + j];
  *(bf16x8*)&xb[i] = v;
}

// ---------------- out = x ----------------
__global__ __launch_bounds__(256) void k_copy_out(const float* __restrict__ x,
                                                  float* __restrict__ out) {
  int i = blockIdx.x * 256 + threadIdx.x;
  ((float4*)out)[i] = ((const float4*)x)[i];
}

// ---------------- gating: softmax + top-8 ----------------
__global__ __launch_bounds__(256) void k_gating(const float* __restrict__ x,
                                                const float* __restrict__ Wg,
                                                int* __restrict__ sel_e,
                                                float* __restrict__ sel_w) {
  int token = blockIdx.x * 4 + (threadIdx.x >> 6);
  int lane = threadIdx.x & 63;
  int e = lane & 31;
  int half = lane >> 5;
  const float* xr = x + (size_t)token * DDIM + half * (DDIM / 2);
  const float* wg = Wg + (size_t)half * (DDIM / 2) * NEXP + e;
  float acc = 0.f;
#pragma unroll 8
  for (int k = 0; k < DDIM / 2; ++k) acc = fmaf(xr[k], wg[k * NEXP], acc);
  acc += __shfl_xor(acc, 32);
  float m = acc;
  for (int off = 16; off; off >>= 1) m = fmaxf(m, __shfl_xor(m, off));
  float p = __expf(acc - m);
  float s = p;
  for (int off = 16; off; off >>= 1) s += __shfl_xor(s, off);
  p /= s;
  float pv = p;
  int my_se = 0;
  float my_sw = 0.f;
  for (int it = 0; it < TOPK; ++it) {
    float mx = pv;
    for (int off = 16; off; off >>= 1) mx = fmaxf(mx, __shfl_xor(mx, off));
    unsigned long long bal = __ballot(pv == mx);
    int sl = __ffsll(bal) - 1;
    int se = sl & 31;
    if (lane == it) { my_se = se; my_sw = mx; }
    if (e == se) pv = -1.f;
  }
  if (lane < TOPK) {
    sel_e[token * TOPK + lane] = my_se;
    sel_w[token * TOPK + lane] = my_sw;
  }
}

// ---------------- deterministic per-expert compaction ----------------
__global__ __launch_bounds__(256) void k_build_lists(const int* __restrict__ sel_e,
                                                     const float* __restrict__ sel_w,
                                                     int* __restrict__ list,
                                                     float* __restrict__ wlist,
                                                     int* __restrict__ count) {
  int e = blockIdx.x;
  int t = threadIdx.x;
  int lane = t & 63, wv = t >> 6;
  __shared__ int wsum[4];
  __shared__ int base;
  if (t == 0) base = 0;
  __syncthreads();
  for (int c = 0; c < B_TOK; c += 256) {
    int b = c + t;
    int flag = 0, slot = 0;
    float w = 0.f;
#pragma unroll
    for (int j = 0; j < TOPK; ++j) {
      if (sel_e[b * TOPK + j] == e) { flag = 1; slot = j; w = sel_w[b * TOPK + j]; }
    }
    unsigned long long bal = __ballot(flag);
    int pre = __popcll(bal & ((1ull << lane) - 1ull));
    int tot = __popcll(bal);
    if (lane == 0) wsum[wv] = tot;
    __syncthreads();
    int off = base;
    for (int i = 0; i < wv; ++i) off += wsum[i];
    if (flag) {
      int pos = off + pre;
      list[e * B_TOK + pos] = (b << 3) | slot;
      wlist[e * B_TOK + pos] = w;
    }
    __syncthreads();
    if (t == 0) base += wsum[0] + wsum[1] + wsum[2] + wsum[3];
    __syncthreads();
  }
  if (t == 0) count[e] = base;
}

// ---------------- W1/W2: f32 [E][R][C] -> bf16 [E][C][R] ----------------
__global__ __launch_bounds__(256) void k_transpose(const float* __restrict__ W1,
                                                   const float* __restrict__ W2,
                                                   bf16_t* __restrict__ W1t,
                                                   bf16_t* __restrict__ W2t) {
  __shared__ bf16_t tile[64][66];
  int z = blockIdx.z;
  const float* in;
  bf16_t* out;
  if (z < NEXP) {
    in = W1 + (size_t)z * DDIM * HDIM;
    out = W1t + (size_t)z * DDIM * HDIM;
  } else {
    in = W2 + (size_t)(z - NEXP) * DDIM * HDIM;
    out = W2t + (size_t)(z - NEXP) * DDIM * HDIM;
  }
  int c0 = blockIdx.x * 64;
  int r0 = blockIdx.y * 64;
  int t = threadIdx.x;
#pragma unroll
  for (int it = 0; it < 16; ++it) {
    int idx = it * 256 + t;
    int r = idx >> 6, c = idx & 63;
    tile[c][r] = (bf16_t)in[(size_t)(r0 + r) * 1024 + c0 + c];
  }
  __syncthreads();
#pragma unroll
  for (int it = 0; it < 8; ++it) {
    int idx = it * 256 + t;
    int rr = idx >> 5, cw = idx & 31;
    unsigned int v = *(const unsigned int*)&tile[rr][cw * 2];
    *((unsigned int*)(out + (size_t)(c0 + rr) * 1024 + r0) + cw) = v;
  }
}

// ---------------- grouped GEMM ----------------
__device__ __forceinline__ void async_load16(const bf16_t* g, bf16_t* l) {
  __builtin_amdgcn_global_load_lds((const __attribute__((address_space(1))) void*)g,
                                   (__attribute__((address_space(3))) void*)l, 16, 0, 0);
}

template <int PHASE>
__global__ __launch_bounds__(256) void k_gemm(const bf16_t* __restrict__ Abase,
                                              const bf16_t* __restrict__ Bt,
                                              const int* __restrict__ list,
                                              const float* __restrict__ wlist,
                                              const int* __restrict__ count,
                                              const float* __restrict__ bias,
                                              bf16_t* __restrict__ hbuf,
                                              float* __restrict__ out) {
  __shared__ bf16_t As[128][64];
  __shared__ bf16_t Bs[128][64];
  const int e = blockIdx.x >> 4;
  const int mt = blockIdx.x & 15;
  const int cnt = count[e];
  const int m0 = mt * 128;
  if (m0 >= cnt) return;
  const int n0 = blockIdx.y * 128;
  const int t = threadIdx.x;
  const int lane = t & 63;
  const int w = t >> 6;
  const int wm = (w >> 1) * 64, wn = (w & 1) * 64;

  const bf16_t* asrc[4];
  const bf16_t* bsrc[4];
#pragma unroll
  for (int i = 0; i < 4; ++i) {
    int row = w * 32 + i * 8 + (lane >> 3);
    int mi = m0 + row;
    if (mi > cnt - 1) mi = cnt - 1;
    int li = list[e * B_TOK + mi];
    int tok = li >> 3, slot = li & 7;
    size_t arow = (PHASE == 1) ? (size_t)tok * DDIM : ((size_t)tok * 8 + slot) * HDIM;
    asrc[i] = Abase + arow + (lane & 7) * 8;
    bsrc[i] = Bt + ((size_t)e * 1024 + n0 + row) * 1024 + (lane & 7) * 8;
  }

  f32x4 acc[4][4] = {};

  for (int ks = 0; ks < 16; ++ks) {
#pragma unroll
    for (int i = 0; i < 4; ++i) {
      async_load16(asrc[i] + ks * 64, &As[w * 32 + i * 8][0]);
      async_load16(bsrc[i] + ks * 64, &Bs[w * 32 + i * 8][0]);
    }
    __syncthreads();
#pragma unroll
    for (int kk = 0; kk < 2; ++kk) {
      bf16x8 af[4], bfr[4];
#pragma unroll
      for (int m = 0; m < 4; ++m)
        af[m] = *(const bf16x8*)&As[wm + m * 16 + (lane & 15)][kk * 32 + (lane >> 4) * 8];
#pragma unroll
      for (int n = 0; n < 4; ++n)
        bfr[n] = *(const bf16x8*)&Bs[wn + n * 16 + (lane & 15)][kk * 32 + (lane >> 4) * 8];
#pragma unroll
      for (int m = 0; m < 4; ++m)
#pragma unroll
        for (int n = 0; n < 4; ++n)
          acc[m][n] = __builtin_amdgcn_mfma_f32_16x16x32_bf16(af[m], bfr[n], acc[m][n], 0, 0, 0);
    }
    __syncthreads();
  }

  float biasv[4];
#pragma unroll
  for (int n = 0; n < 4; ++n) biasv[n] = bias[e * 1024 + n0 + wn + n * 16 + (lane & 15)];

#pragma unroll
  for (int m = 0; m < 4; ++m) {
#pragma unroll
    for (int j = 0; j < 4; ++j) {
      int gm = m0 + wm + m * 16 + (lane >> 4) * 4 + j;
      if (gm < cnt) {
        int li = list[e * B_TOK + gm];
        int tok = li >> 3, slot = li & 7;
        if (PHASE == 1) {
          bf16_t* hr = hbuf + ((size_t)tok * 8 + slot) * HDIM + n0 + wn + (lane & 15);
#pragma unroll
          for (int n = 0; n < 4; ++n) {
            float v = acc[m][n][j] + biasv[n];
            hr[n * 16] = (bf16_t)(v > 0.f ? v : 0.f);
          }
        } else {
          float gw = wlist[e * B_TOK + gm];
          float* orow = out + (size_t)tok * DDIM + n0 + wn + (lane & 15);
#pragma unroll
          for (int n = 0; n < 4; ++n) {
            float v = (acc[m][n][j] + biasv[n]) * gw;
            unsafeAtomicAdd(&orow[n * 16], v);
          }
        }
      }
    }
  }
}

extern "C" void kernel_launch(void* const* d_in, const int* in_sizes, int n_in,
                              void* d_out, int out_size, void* d_ws, size_t ws_size,
                              hipStream_t stream) {
  const float* x = (const float*)d_in[0];
  const float* Wg = (const float*)d_in[1];
  const float* W1 = (const float*)d_in[2];
  const float* b1 = (const float*)d_in[3];
  const float* W2 = (const float*)d_in[4];
  const float* b2 = (const float*)d_in[5];
  float* out = (float*)d_out;

  char* ws = (char*)d_ws;
  bf16_t* xb = (bf16_t*)ws;   ws += (size_t)B_TOK * DDIM * 2;
  bf16_t* W1t = (bf16_t*)ws;  ws += (size_t)NEXP * DDIM * HDIM * 2;
  bf16_t* W2t = (bf16_t*)ws;  ws += (size_t)NEXP * DDIM * HDIM * 2;
  bf16_t* hbuf = (bf16_t*)ws; ws += (size_t)B_TOK * TOPK * HDIM * 2;
  int* sel_e = (int*)ws;      ws += (size_t)B_TOK * TOPK * 4;
  float* sel_w = (float*)ws;  ws += (size_t)B_TOK * TOPK * 4;
  int* list = (int*)ws;       ws += (size_t)NEXP * B_TOK * 4;
  float* wlist = (float*)ws;  ws += (size_t)NEXP * B_TOK * 4;
  int* count = (int*)ws;      ws += (size_t)NEXP * 4;

  k_convert_x<<<1024, 256, 0, stream>>>(x, xb);
  k_gating<<<512, 256, 0, stream>>>(x, Wg, sel_e, sel_w);
  k_build_lists<<<32, 256, 0, stream>>>(sel_e, sel_w, list, wlist, count);
  k_transpose<<<dim3(16, 16, 64), 256, 0, stream>>>(W1, W2, W1t, W2t);
  k_copy_out<<<2048, 256, 0, stream>>>(x, out);
  k_gemm<1><<<dim3(512, 8), 256, 0, stream>>>(xb, W1t, list, wlist, count, b1, hbuf, out);
  k_gemm<2><<<dim3(512, 8), 256, 0, stream>>>(hbuf, W2t, list, wlist, count, b2, hbuf, out);
}

// Round 2
// 364.907 us; speedup vs baseline: 1.7085x; 1.7085x over previous
//
#include <hip/hip_runtime.h>
#include <hip/hip_bf16.h>

#define B_TOK 2048
#define DDIM 1024
#define NEXP 32
#define HDIM 1024
#define TOPK 8

typedef __bf16 bf16_t;
typedef __bf16 bf16x8 __attribute__((ext_vector_type(8)));
typedef float f32x4 __attribute__((ext_vector_type(4)));

// ---------------- x -> bf16 ----------------
__global__ __launch_bounds__(256) void k_convert_x(const float* __restrict__ x,
                                                   bf16_t* __restrict__ xb) {
  int i = (blockIdx.x * 256 + threadIdx.x) * 8;
  bf16x8 v;
#pragma unroll
  for (int j = 0; j < 8; ++j) v[j] = (bf16_t)x[i + j];
  *(bf16x8*)&xb[i] = v;
}

// ---------------- out = x ----------------
__global__ __launch_bounds__(256) void k_copy_out(const float* __restrict__ x,
                                                  float* __restrict__ out) {
  int i = blockIdx.x * 256 + threadIdx.x;
  ((float4*)out)[i] = ((const float4*)x)[i];
}

// ---------------- gating: softmax + top-8 ----------------
__global__ __launch_bounds__(256) void k_gating(const float* __restrict__ x,
                                                const float* __restrict__ Wg,
                                                int* __restrict__ sel_e,
                                                float* __restrict__ sel_w) {
  int token = blockIdx.x * 4 + (threadIdx.x >> 6);
  int lane = threadIdx.x & 63;
  int e = lane & 31;
  int half = lane >> 5;
  const float* xr = x + (size_t)token * DDIM + half * (DDIM / 2);
  const float* wg = Wg + (size_t)half * (DDIM / 2) * NEXP + e;
  float acc = 0.f;
#pragma unroll 8
  for (int k = 0; k < DDIM / 2; ++k) acc = fmaf(xr[k], wg[k * NEXP], acc);
  acc += __shfl_xor(acc, 32);
  float m = acc;
  for (int off = 16; off; off >>= 1) m = fmaxf(m, __shfl_xor(m, off));
  float p = __expf(acc - m);
  float s = p;
  for (int off = 16; off; off >>= 1) s += __shfl_xor(s, off);
  p /= s;
  float pv = p;
  int my_se = 0;
  float my_sw = 0.f;
  for (int it = 0; it < TOPK; ++it) {
    float mx = pv;
    for (int off = 16; off; off >>= 1) mx = fmaxf(mx, __shfl_xor(mx, off));
    unsigned long long bal = __ballot(pv == mx);
    int sl = __ffsll(bal) - 1;
    int se = sl & 31;
    if (lane == it) { my_se = se; my_sw = mx; }
    if (e == se) pv = -1.f;
  }
  if (lane < TOPK) {
    sel_e[token * TOPK + lane] = my_se;
    sel_w[token * TOPK + lane] = my_sw;
  }
}

// ---------------- deterministic per-expert compaction ----------------
__global__ __launch_bounds__(256) void k_build_lists(const int* __restrict__ sel_e,
                                                     const float* __restrict__ sel_w,
                                                     int* __restrict__ list,
                                                     float* __restrict__ wlist,
                                                     int* __restrict__ count) {
  int e = blockIdx.x;
  int t = threadIdx.x;
  int lane = t & 63, wv = t >> 6;
  __shared__ int wsum[4];
  __shared__ int base;
  if (t == 0) base = 0;
  __syncthreads();
  for (int c = 0; c < B_TOK; c += 256) {
    int b = c + t;
    int flag = 0, slot = 0;
    float w = 0.f;
#pragma unroll
    for (int j = 0; j < TOPK; ++j) {
      if (sel_e[b * TOPK + j] == e) { flag = 1; slot = j; w = sel_w[b * TOPK + j]; }
    }
    unsigned long long bal = __ballot(flag);
    int pre = __popcll(bal & ((1ull << lane) - 1ull));
    int tot = __popcll(bal);
    if (lane == 0) wsum[wv] = tot;
    __syncthreads();
    int off = base;
    for (int i = 0; i < wv; ++i) off += wsum[i];
    if (flag) {
      int pos = off + pre;
      list[e * B_TOK + pos] = (b << 3) | slot;
      wlist[e * B_TOK + pos] = w;
    }
    __syncthreads();
    if (t == 0) base += wsum[0] + wsum[1] + wsum[2] + wsum[3];
    __syncthreads();
  }
  if (t == 0) count[e] = base;
}

// ---------------- W1/W2: f32 [E][R][C] -> bf16 [E][C][R] ----------------
__global__ __launch_bounds__(256) void k_transpose(const float* __restrict__ W1,
                                                   const float* __restrict__ W2,
                                                   bf16_t* __restrict__ W1t,
                                                   bf16_t* __restrict__ W2t) {
  __shared__ bf16_t tile[64][66];
  int z = blockIdx.z;
  const float* in;
  bf16_t* out;
  if (z < NEXP) {
    in = W1 + (size_t)z * DDIM * HDIM;
    out = W1t + (size_t)z * DDIM * HDIM;
  } else {
    in = W2 + (size_t)(z - NEXP) * DDIM * HDIM;
    out = W2t + (size_t)(z - NEXP) * DDIM * HDIM;
  }
  int c0 = blockIdx.x * 64;
  int r0 = blockIdx.y * 64;
  int t = threadIdx.x;
#pragma unroll
  for (int it = 0; it < 16; ++it) {
    int idx = it * 256 + t;
    int r = idx >> 6, c = idx & 63;
    tile[c][r] = (bf16_t)in[(size_t)(r0 + r) * 1024 + c0 + c];
  }
  __syncthreads();
#pragma unroll
  for (int it = 0; it < 8; ++it) {
    int idx = it * 256 + t;
    int rr = idx >> 5, cw = idx & 31;
    unsigned int v = *(const unsigned int*)&tile[rr][cw * 2];
    *((unsigned int*)(out + (size_t)(c0 + rr) * 1024 + r0) + cw) = v;
  }
}

// ---------------- grouped GEMM: dbuf + prefetch + T2 swizzle + XCD chunk ----
__device__ __forceinline__ void async_load16(const bf16_t* g, bf16_t* l) {
  __builtin_amdgcn_global_load_lds((const __attribute__((address_space(1))) void*)g,
                                   (__attribute__((address_space(3))) void*)l, 16, 0, 0);
}

template <int PHASE>
__global__ __launch_bounds__(256, 2) void k_gemm(const bf16_t* __restrict__ Abase,
                                                 const bf16_t* __restrict__ Bt,
                                                 const int* __restrict__ list,
                                                 const float* __restrict__ wlist,
                                                 const int* __restrict__ count,
                                                 const float* __restrict__ bias,
                                                 bf16_t* __restrict__ hbuf,
                                                 float* __restrict__ out) {
  __shared__ bf16_t As[2][128][64];
  __shared__ bf16_t Bs[2][128][64];

  // XCD-chunked 1-D grid: chunk of 512 consecutive works per XCD.
  const int phys = blockIdx.x;
  const int wk = (phys & 7) * 512 + (phys >> 3);
  const int e = wk >> 7;        // 128 works per expert
  const int rem = wk & 127;
  const int y = rem >> 4;       // n-tile (8), same-y m-tiles consecutive -> share B slice in L2
  const int mt = rem & 15;      // m-tile (16)

  const int cnt = count[e];
  const int m0 = mt * 128;
  if (m0 >= cnt) return;
  const int n0 = y * 128;

  const int t = threadIdx.x;
  const int lane = t & 63;
  const int w = t >> 6;
  const int wm = (w >> 1) * 64, wn = (w & 1) * 64;
  const int l7 = lane & 7;
  const int hi = lane >> 4;
  // pre-swizzled global source slot: content for LDS slot (lane&7) of row (..+lane>>3)
  const int srs = ((l7 ^ (lane >> 3))) * 8;

  const bf16_t* asrc[4];
  const bf16_t* bsrc[4];
#pragma unroll
  for (int i = 0; i < 4; ++i) {
    int row = w * 32 + i * 8 + (lane >> 3);
    int mi = m0 + row;
    if (mi > cnt - 1) mi = cnt - 1;
    int li = list[e * B_TOK + mi];
    int tok = li >> 3, slot = li & 7;
    size_t arow = (PHASE == 1) ? (size_t)tok * DDIM : ((size_t)tok * 8 + slot) * HDIM;
    asrc[i] = Abase + arow + srs;
    bsrc[i] = Bt + ((size_t)e * 1024 + n0 + row) * 1024 + srs;
  }

  f32x4 acc[4][4] = {};

  auto STAGE = [&](int buf, int ks) {
#pragma unroll
    for (int i = 0; i < 4; ++i) {
      async_load16(asrc[i] + ks * 64, &As[buf][w * 32 + i * 8][0]);
      async_load16(bsrc[i] + ks * 64, &Bs[buf][w * 32 + i * 8][0]);
    }
  };

  STAGE(0, 0);
  __syncthreads();

#pragma unroll 2
  for (int ks = 0; ks < 16; ++ks) {
    const int buf = ks & 1;
    if (ks < 15) STAGE(buf ^ 1, ks + 1);
#pragma unroll
    for (int kk = 0; kk < 2; ++kk) {
      // swizzled read: global slot g = kk*4+hi lives at LDS slot g^(row&7), row&7 == lane&7
      const int ca = (((kk << 2) + hi) ^ l7) << 3;
      bf16x8 af[4], bfr[4];
#pragma unroll
      for (int m = 0; m < 4; ++m)
        af[m] = *(const bf16x8*)&As[buf][wm + m * 16 + (lane & 15)][ca];
#pragma unroll
      for (int n = 0; n < 4; ++n)
        bfr[n] = *(const bf16x8*)&Bs[buf][wn + n * 16 + (lane & 15)][ca];
#pragma unroll
      for (int m = 0; m < 4; ++m)
#pragma unroll
        for (int n = 0; n < 4; ++n)
          acc[m][n] = __builtin_amdgcn_mfma_f32_16x16x32_bf16(af[m], bfr[n], acc[m][n], 0, 0, 0);
    }
    __syncthreads();
  }

  float biasv[4];
#pragma unroll
  for (int n = 0; n < 4; ++n) biasv[n] = bias[e * 1024 + n0 + wn + n * 16 + (lane & 15)];

#pragma unroll
  for (int m = 0; m < 4; ++m) {
#pragma unroll
    for (int j = 0; j < 4; ++j) {
      int gm = m0 + wm + m * 16 + (lane >> 4) * 4 + j;
      if (gm < cnt) {
        int li = list[e * B_TOK + gm];
        int tok = li >> 3, slot = li & 7;
        if (PHASE == 1) {
          bf16_t* hr = hbuf + ((size_t)tok * 8 + slot) * HDIM + n0 + wn + (lane & 15);
#pragma unroll
          for (int n = 0; n < 4; ++n) {
            float v = acc[m][n][j] + biasv[n];
            hr[n * 16] = (bf16_t)(v > 0.f ? v : 0.f);
          }
        } else {
          float gw = wlist[e * B_TOK + gm];
          float* orow = out + (size_t)tok * DDIM + n0 + wn + (lane & 15);
#pragma unroll
          for (int n = 0; n < 4; ++n) {
            float v = (acc[m][n][j] + biasv[n]) * gw;
            unsafeAtomicAdd(&orow[n * 16], v);
          }
        }
      }
    }
  }
}

extern "C" void kernel_launch(void* const* d_in, const int* in_sizes, int n_in,
                              void* d_out, int out_size, void* d_ws, size_t ws_size,
                              hipStream_t stream) {
  const float* x = (const float*)d_in[0];
  const float* Wg = (const float*)d_in[1];
  const float* W1 = (const float*)d_in[2];
  const float* b1 = (const float*)d_in[3];
  const float* W2 = (const float*)d_in[4];
  const float* b2 = (const float*)d_in[5];
  float* out = (float*)d_out;

  char* ws = (char*)d_ws;
  bf16_t* xb = (bf16_t*)ws;   ws += (size_t)B_TOK * DDIM * 2;
  bf16_t* W1t = (bf16_t*)ws;  ws += (size_t)NEXP * DDIM * HDIM * 2;
  bf16_t* W2t = (bf16_t*)ws;  ws += (size_t)NEXP * DDIM * HDIM * 2;
  bf16_t* hbuf = (bf16_t*)ws; ws += (size_t)B_TOK * TOPK * HDIM * 2;
  int* sel_e = (int*)ws;      ws += (size_t)B_TOK * TOPK * 4;
  float* sel_w = (float*)ws;  ws += (size_t)B_TOK * TOPK * 4;
  int* list = (int*)ws;       ws += (size_t)NEXP * B_TOK * 4;
  float* wlist = (float*)ws;  ws += (size_t)NEXP * B_TOK * 4;
  int* count = (int*)ws;      ws += (size_t)NEXP * 4;

  k_convert_x<<<1024, 256, 0, stream>>>(x, xb);
  k_gating<<<512, 256, 0, stream>>>(x, Wg, sel_e, sel_w);
  k_build_lists<<<32, 256, 0, stream>>>(sel_e, sel_w, list, wlist, count);
  k_transpose<<<dim3(16, 16, 64), 256, 0, stream>>>(W1, W2, W1t, W2t);
  k_copy_out<<<2048, 256, 0, stream>>>(x, out);
  k_gemm<1><<<4096, 256, 0, stream>>>(xb, W1t, list, wlist, count, b1, hbuf, out);
  k_gemm<2><<<4096, 256, 0, stream>>>(hbuf, W2t, list, wlist, count, b2, hbuf, out);
}

// Round 3
// 321.186 us; speedup vs baseline: 1.9411x; 1.1361x over previous
//
#include <hip/hip_runtime.h>
#include <hip/hip_bf16.h>

#define B_TOK 2048
#define DDIM 1024
#define NEXP 32
#define HDIM 1024
#define TOPK 8

typedef __bf16 bf16_t;
typedef __bf16 bf16x8 __attribute__((ext_vector_type(8)));
typedef float f32x4 __attribute__((ext_vector_type(4)));

// ---------------- x -> bf16 ----------------
__global__ __launch_bounds__(256) void k_convert_x(const float* __restrict__ x,
                                                   bf16_t* __restrict__ xb) {
  int i = (blockIdx.x * 256 + threadIdx.x) * 8;
  bf16x8 v;
#pragma unroll
  for (int j = 0; j < 8; ++j) v[j] = (bf16_t)x[i + j];
  *(bf16x8*)&xb[i] = v;
}

// ---------------- out = x ----------------
__global__ __launch_bounds__(256) void k_copy_out(const float* __restrict__ x,
                                                  float* __restrict__ out) {
  int i = blockIdx.x * 256 + threadIdx.x;
  ((float4*)out)[i] = ((const float4*)x)[i];
}

// ---------------- gating: softmax + top-8 ----------------
__global__ __launch_bounds__(256) void k_gating(const float* __restrict__ x,
                                                const float* __restrict__ Wg,
                                                int* __restrict__ sel_e,
                                                float* __restrict__ sel_w) {
  int token = blockIdx.x * 4 + (threadIdx.x >> 6);
  int lane = threadIdx.x & 63;
  int e = lane & 31;
  int half = lane >> 5;
  const float* xr = x + (size_t)token * DDIM + half * (DDIM / 2);
  const float* wg = Wg + (size_t)half * (DDIM / 2) * NEXP + e;
  float acc = 0.f;
#pragma unroll 8
  for (int k = 0; k < DDIM / 2; ++k) acc = fmaf(xr[k], wg[k * NEXP], acc);
  acc += __shfl_xor(acc, 32);
  float m = acc;
  for (int off = 16; off; off >>= 1) m = fmaxf(m, __shfl_xor(m, off));
  float p = __expf(acc - m);
  float s = p;
  for (int off = 16; off; off >>= 1) s += __shfl_xor(s, off);
  p /= s;
  float pv = p;
  int my_se = 0;
  float my_sw = 0.f;
  for (int it = 0; it < TOPK; ++it) {
    float mx = pv;
    for (int off = 16; off; off >>= 1) mx = fmaxf(mx, __shfl_xor(mx, off));
    unsigned long long bal = __ballot(pv == mx);
    int sl = __ffsll(bal) - 1;
    int se = sl & 31;
    if (lane == it) { my_se = se; my_sw = mx; }
    if (e == se) pv = -1.f;
  }
  if (lane < TOPK) {
    sel_e[token * TOPK + lane] = my_se;
    sel_w[token * TOPK + lane] = my_sw;
  }
}

// ---------------- deterministic per-expert compaction ----------------
__global__ __launch_bounds__(256) void k_build_lists(const int* __restrict__ sel_e,
                                                     const float* __restrict__ sel_w,
                                                     int* __restrict__ list,
                                                     float* __restrict__ wlist,
                                                     int* __restrict__ count) {
  int e = blockIdx.x;
  int t = threadIdx.x;
  int lane = t & 63, wv = t >> 6;
  __shared__ int wsum[4];
  __shared__ int base;
  if (t == 0) base = 0;
  __syncthreads();
  for (int c = 0; c < B_TOK; c += 256) {
    int b = c + t;
    int flag = 0, slot = 0;
    float w = 0.f;
#pragma unroll
    for (int j = 0; j < TOPK; ++j) {
      if (sel_e[b * TOPK + j] == e) { flag = 1; slot = j; w = sel_w[b * TOPK + j]; }
    }
    unsigned long long bal = __ballot(flag);
    int pre = __popcll(bal & ((1ull << lane) - 1ull));
    int tot = __popcll(bal);
    if (lane == 0) wsum[wv] = tot;
    __syncthreads();
    int off = base;
    for (int i = 0; i < wv; ++i) off += wsum[i];
    if (flag) {
      int pos = off + pre;
      list[e * B_TOK + pos] = (b << 3) | slot;
      wlist[e * B_TOK + pos] = w;
    }
    __syncthreads();
    if (t == 0) base += wsum[0] + wsum[1] + wsum[2] + wsum[3];
    __syncthreads();
  }
  if (t == 0) count[e] = base;
}

// ---------------- W1/W2: f32 [E][R][C] -> bf16 [E][C][R] ----------------
__global__ __launch_bounds__(256) void k_transpose(const float* __restrict__ W1,
                                                   const float* __restrict__ W2,
                                                   bf16_t* __restrict__ W1t,
                                                   bf16_t* __restrict__ W2t) {
  __shared__ bf16_t tile[64][66];
  int z = blockIdx.z;
  const float* in;
  bf16_t* out;
  if (z < NEXP) {
    in = W1 + (size_t)z * DDIM * HDIM;
    out = W1t + (size_t)z * DDIM * HDIM;
  } else {
    in = W2 + (size_t)(z - NEXP) * DDIM * HDIM;
    out = W2t + (size_t)(z - NEXP) * DDIM * HDIM;
  }
  int c0 = blockIdx.x * 64;
  int r0 = blockIdx.y * 64;
  int t = threadIdx.x;
#pragma unroll
  for (int it = 0; it < 16; ++it) {
    int idx = it * 256 + t;
    int r = idx >> 6, c = idx & 63;
    tile[c][r] = (bf16_t)in[(size_t)(r0 + r) * 1024 + c0 + c];
  }
  __syncthreads();
#pragma unroll
  for (int it = 0; it < 8; ++it) {
    int idx = it * 256 + t;
    int rr = idx >> 5, cw = idx & 31;
    unsigned int v = *(const unsigned int*)&tile[rr][cw * 2];
    *((unsigned int*)(out + (size_t)(c0 + rr) * 1024 + r0) + cw) = v;
  }
}

// ============ grouped GEMM: 256x256, 8-wave, 8-phase counted-vmcnt ==========
__device__ __forceinline__ void async_load16(const bf16_t* g, bf16_t* l) {
  __builtin_amdgcn_global_load_lds((const __attribute__((address_space(1))) void*)g,
                                   (__attribute__((address_space(3))) void*)l, 16, 0, 0);
}

#define BAR __builtin_amdgcn_s_barrier();
#define LG0 asm volatile("s_waitcnt lgkmcnt(0)" ::: "memory"); __builtin_amdgcn_sched_barrier(0);
#define WV(N) asm volatile("s_waitcnt vmcnt(" #N ")" ::: "memory");
#define PR1 __builtin_amdgcn_s_setprio(1);
#define PR0 __builtin_amdgcn_s_setprio(0);

#define RD_A(BUF, MQ)                                                         \
  {                                                                           \
    _Pragma("unroll") for (int mm = 0; mm < 4; ++mm)                          \
        _Pragma("unroll") for (int ks = 0; ks < 2; ++ks)                      \
            a[mm][ks] = *(const bf16x8*)&As[BUF][MQ][mm * 32 + wr16 + lr]     \
                                           [(((ks << 2) | hi) ^ l7) << 3];    \
  }
#define RD_B(BUF, NQ, DST)                                                    \
  {                                                                           \
    _Pragma("unroll") for (int nn = 0; nn < 2; ++nn)                          \
        _Pragma("unroll") for (int ks = 0; ks < 2; ++ks)                      \
            DST[nn][ks] = *(const bf16x8*)&Bs[BUF][NQ][nn * 64 + wc16 + lr]   \
                                             [(((ks << 2) | hi) ^ l7) << 3];  \
  }
#define MM16(MQ, NQ, BSET)                                                    \
  {                                                                           \
    _Pragma("unroll") for (int mm = 0; mm < 4; ++mm)                          \
        _Pragma("unroll") for (int nn = 0; nn < 2; ++nn)                      \
            _Pragma("unroll") for (int ks = 0; ks < 2; ++ks)                  \
                acc[MQ * 4 + mm][NQ * 2 + nn] =                               \
                    __builtin_amdgcn_mfma_f32_16x16x32_bf16(                  \
                        a[mm][ks], BSET[nn][ks],                              \
                        acc[MQ * 4 + mm][NQ * 2 + nn], 0, 0, 0);              \
  }
#define IA(KT, H, BUF)                                                        \
  {                                                                           \
    async_load16(aptr[H][0] + (KT)*64, &As[BUF][H][w * 8][0]);                \
    async_load16(aptr[H][1] + (KT)*64, &As[BUF][H][64 + w * 8][0]);           \
  }
#define IB(KT, H, BUF)                                                        \
  {                                                                           \
    async_load16(bptr[H][0] + (KT)*64, &Bs[BUF][H][w * 8][0]);                \
    async_load16(bptr[H][1] + (KT)*64, &Bs[BUF][H][64 + w * 8][0]);           \
  }

template <int PHASE>
__global__ __launch_bounds__(512, 2) void k_gemm(const bf16_t* __restrict__ Abase,
                                                 const bf16_t* __restrict__ Bt,
                                                 const int* __restrict__ list,
                                                 const float* __restrict__ wlist,
                                                 const int* __restrict__ count,
                                                 const float* __restrict__ bias,
                                                 bf16_t* __restrict__ hbuf,
                                                 float* __restrict__ out) {
  __shared__ bf16_t As[2][2][128][64];  // [buf][half][row][k]
  __shared__ bf16_t Bs[2][2][128][64];

  // XCD-chunked work mapping: 1024 phys blocks, 128 per XCD chunk.
  const int phys = blockIdx.x;
  const int wk = (phys & 7) * 128 + (phys >> 3);
  const int e = wk >> 5;        // 32 works per expert
  const int y = (wk >> 3) & 3;  // n-tile (4)
  const int mt = wk & 7;        // m-tile (8); same-(e,y) m-tiles consecutive

  const int cnt = count[e];
  const int m0 = mt * 256;
  if (m0 >= cnt) return;
  const int n0 = y * 256;

  const int t = threadIdx.x;
  const int lane = t & 63;
  const int w = t >> 6;             // wave 0..7
  const int wr16 = (w >> 2) << 4;   // 2 M-waves
  const int wc16 = (w & 3) << 4;    // 4 N-waves
  const int lr = lane & 15;
  const int hi = lane >> 4;
  const int l7 = lane & 7;
  const int srs = ((lane & 7) ^ ((lane >> 3) & 7)) << 3;  // pre-swizzled src slot

  const int* lrow = list + e * B_TOK;

  const bf16_t* aptr[2][2];
  const bf16_t* bptr[2][2];
#pragma unroll
  for (int h = 0; h < 2; ++h)
#pragma unroll
    for (int r = 0; r < 2; ++r) {
      int row = h * 128 + r * 64 + w * 8 + (lane >> 3);
      int mi = m0 + row;
      if (mi > cnt - 1) mi = cnt - 1;
      int li = lrow[mi];
      int tok = li >> 3, slot = li & 7;
      size_t arow = (PHASE == 1) ? (size_t)tok * DDIM : ((size_t)tok * 8 + slot) * HDIM;
      aptr[h][r] = Abase + arow + srs;
      bptr[h][r] = Bt + ((size_t)e * 1024 + n0 + row) * 1024 + srs;
    }

  f32x4 acc[8][4] = {};
  bf16x8 a[4][2], bn0[2][2], bn1[2][2];

  // Prologue: A-h0(0) B-h0(0) A-h1(0) B-h1(0) A-h0(1) B-h0(1)
  IA(0, 0, 0) IB(0, 0, 0) IA(0, 1, 0) IB(0, 1, 0) IA(1, 0, 1) IB(1, 0, 1)
  WV(8) BAR

#pragma unroll 1
  for (int i = 0; i < 7; ++i) {
    const int kt = 2 * i;
    // p0: Q0(kt)  issue A-h1(kt+1)
    RD_A(0, 0) RD_B(0, 0, bn0) IA(kt + 1, 1, 1) WV(6) BAR LG0 PR1 MM16(0, 0, bn0) PR0 BAR
    // p1: Q1(kt)  issue B-h1(kt+1)
    RD_B(0, 1, bn1) IB(kt + 1, 1, 1) BAR LG0 PR1 MM16(0, 1, bn1) PR0 BAR
    // p2: Q2(kt)  issue A-h0(kt+2)
    RD_A(0, 1) IA(kt + 2, 0, 0) BAR LG0 PR1 MM16(1, 0, bn0) PR0 BAR
    // p3: Q3(kt)  issue B-h0(kt+2)
    IB(kt + 2, 0, 0) WV(8) BAR LG0 PR1 MM16(1, 1, bn1) PR0 BAR
    // p4: Q0(kt+1) issue A-h1(kt+2)
    RD_A(1, 0) RD_B(1, 0, bn0) IA(kt + 2, 1, 0) WV(6) BAR LG0 PR1 MM16(0, 0, bn0) PR0 BAR
    // p5: Q1(kt+1) issue B-h1(kt+2)
    RD_B(1, 1, bn1) IB(kt + 2, 1, 0) BAR LG0 PR1 MM16(0, 1, bn1) PR0 BAR
    // p6: Q2(kt+1) issue A-h0(kt+3)
    RD_A(1, 1) IA(kt + 3, 0, 1) BAR LG0 PR1 MM16(1, 0, bn0) PR0 BAR
    // p7: Q3(kt+1) issue B-h0(kt+3)
    IB(kt + 3, 0, 1) WV(8) BAR LG0 PR1 MM16(1, 1, bn1) PR0 BAR
  }
  // Tail: tiles 14 (buf0) and 15 (buf1); only A/B-h1(15) left to issue.
  RD_A(0, 0) RD_B(0, 0, bn0) IA(15, 1, 1) WV(6) BAR LG0 PR1 MM16(0, 0, bn0) PR0 BAR
  RD_B(0, 1, bn1) IB(15, 1, 1) BAR LG0 PR1 MM16(0, 1, bn1) PR0 BAR
  RD_A(0, 1) BAR LG0 PR1 MM16(1, 0, bn0) PR0 BAR
  WV(4) BAR LG0 PR1 MM16(1, 1, bn1) PR0 BAR
  RD_A(1, 0) RD_B(1, 0, bn0) WV(0) BAR LG0 PR1 MM16(0, 0, bn0) PR0 BAR
  RD_B(1, 1, bn1) BAR LG0 PR1 MM16(0, 1, bn1) PR0 BAR
  RD_A(1, 1) BAR LG0 PR1 MM16(1, 0, bn0) PR0 BAR
  BAR LG0 PR1 MM16(1, 1, bn1) PR0 BAR

  // Epilogue
  float biasv[4];
#pragma unroll
  for (int n = 0; n < 4; ++n) biasv[n] = bias[e * 1024 + n0 + n * 64 + wc16 + lr];

#pragma unroll
  for (int m = 0; m < 8; ++m) {
#pragma unroll
    for (int j = 0; j < 4; ++j) {
      int gm = m0 + m * 32 + wr16 + hi * 4 + j;
      if (gm < cnt) {
        int li = lrow[gm];
        int tok = li >> 3, slot = li & 7;
        if (PHASE == 1) {
          bf16_t* hr = hbuf + ((size_t)tok * 8 + slot) * HDIM + n0;
#pragma unroll
          for (int n = 0; n < 4; ++n) {
            float v = acc[m][n][j] + biasv[n];
            hr[n * 64 + wc16 + lr] = (bf16_t)(v > 0.f ? v : 0.f);
          }
        } else {
          float gw = wlist[e * B_TOK + gm];
          float* orow = out + (size_t)tok * DDIM + n0;
#pragma unroll
          for (int n = 0; n < 4; ++n) {
            float v = (acc[m][n][j] + biasv[n]) * gw;
            unsafeAtomicAdd(&orow[n * 64 + wc16 + lr], v);
          }
        }
      }
    }
  }
}

extern "C" void kernel_launch(void* const* d_in, const int* in_sizes, int n_in,
                              void* d_out, int out_size, void* d_ws, size_t ws_size,
                              hipStream_t stream) {
  const float* x = (const float*)d_in[0];
  const float* Wg = (const float*)d_in[1];
  const float* W1 = (const float*)d_in[2];
  const float* b1 = (const float*)d_in[3];
  const float* W2 = (const float*)d_in[4];
  const float* b2 = (const float*)d_in[5];
  float* out = (float*)d_out;

  char* ws = (char*)d_ws;
  bf16_t* xb = (bf16_t*)ws;   ws += (size_t)B_TOK * DDIM * 2;
  bf16_t* W1t = (bf16_t*)ws;  ws += (size_t)NEXP * DDIM * HDIM * 2;
  bf16_t* W2t = (bf16_t*)ws;  ws += (size_t)NEXP * DDIM * HDIM * 2;
  bf16_t* hbuf = (bf16_t*)ws; ws += (size_t)B_TOK * TOPK * HDIM * 2;
  int* sel_e = (int*)ws;      ws += (size_t)B_TOK * TOPK * 4;
  float* sel_w = (float*)ws;  ws += (size_t)B_TOK * TOPK * 4;
  int* list = (int*)ws;       ws += (size_t)NEXP * B_TOK * 4;
  float* wlist = (float*)ws;  ws += (size_t)NEXP * B_TOK * 4;
  int* count = (int*)ws;      ws += (size_t)NEXP * 4;

  k_convert_x<<<1024, 256, 0, stream>>>(x, xb);
  k_gating<<<512, 256, 0, stream>>>(x, Wg, sel_e, sel_w);
  k_build_lists<<<32, 256, 0, stream>>>(sel_e, sel_w, list, wlist, count);
  k_transpose<<<dim3(16, 16, 64), 256, 0, stream>>>(W1, W2, W1t, W2t);
  k_copy_out<<<2048, 256, 0, stream>>>(x, out);
  k_gemm<1><<<1024, 512, 0, stream>>>(xb, W1t, list, wlist, count, b1, hbuf, out);
  k_gemm<2><<<1024, 512, 0, stream>>>(hbuf, W2t, list, wlist, count, b2, hbuf, out);
}